// Round 5
// baseline (156.711 us; speedup 1.0000x reference)
//
#include <hip/hip_runtime.h>

// YOLO-v1 style loss, fused single pass + separate final reduce.
// pred: (8192,7,7,30) f32, gt: (8192,7,7,30) f32 -> scalar f32 (= total/8192).
//
// R4 post-mortem: scatter loads serialize (VGPR-tight -> low MLP; 64 lines
// per VMEM instr -> L1 tag-path floor). R5: coalesced float4 staging into
// LDS (linear copy, no div/mod), 128 cells / 128 threads / 30KB LDS ->
// 5 blocks/CU, 10 waves/CU, ~240 lines in flight per wave during staging.
// Compute reads cell records from LDS as stride-30 float2 (4-way bank
// conflict, ~1.6x on a ~2us LDS phase -- acceptable). No atomics (R4).

#define NCH 30
#define TPB 128
#define CELLS 128
#define NV4 ((CELLS * NCH) / 4)   // 960 float4 per tensor per block
#define INV_B (1.0f / 8192.0f)

__global__ __launch_bounds__(TPB)
void yolo_main(const float* __restrict__ pred,
               const float* __restrict__ gt,
               float* __restrict__ partial,
               int ncells)
{
    __shared__ float sp[CELLS * NCH];   // 15360 B linear pred tile
    __shared__ float sg[CELLS * NCH];   // 15360 B linear gt tile
    __shared__ float wsum[TPB / 64];

    const int tid = threadIdx.x;
    const long long baseF = (long long)blockIdx.x * CELLS * NCH;

    const float4* gp4 = (const float4*)(pred + baseF);
    const float4* gg4 = (const float4*)(gt + baseF);
    float4* lp4 = (float4*)sp;
    float4* lg4 = (float4*)sg;

    // ---- stage: 960 float4 per tensor, 8 rounds of 128 threads (last half)
    // Fully unrolled; loads first (MLP), ds_writes consume as vmcnt drains.
    float4 vp[8], vg[8];
#pragma unroll
    for (int i = 0; i < 8; ++i) {
        const int idx = tid + i * TPB;
        if (idx < NV4) { vp[i] = gp4[idx]; vg[i] = gg4[idx]; }
    }
#pragma unroll
    for (int i = 0; i < 8; ++i) {
        const int idx = tid + i * TPB;
        if (idx < NV4) { lp4[idx] = vp[i]; lg4[idx] = vg[i]; }
    }
    __syncthreads();

    // ---- per-cell loss (verified math, absmax == 0 across R1-R4)
    const float2* cp = (const float2*)(sp + tid * NCH);
    const float2* cg = (const float2*)(sg + tid * NCH);

    float2 p[15];
#pragma unroll
    for (int j = 0; j < 15; ++j) p[j] = cp[j];

    const float2 g0 = cg[0];
    const float2 g1 = cg[1];
    const float2 g2 = cg[2];          // .x = obj flag
    float2 gcl[10];
#pragma unroll
    for (int j = 0; j < 10; ++j) gcl[j] = cg[5 + j];

    const float gx = g0.x, gy = g0.y, gw = g1.x, gh = g1.y;
    const float gc = g2.x;
    const float obj   = (gc > 0.0f) ? 1.0f : 0.0f;
    const float noobj = (gc == 0.0f) ? 1.0f : 0.0f;

    const float ghw = 3.5f * gw, ghh = 3.5f * gh;   // 0.5*GRID*wh
    const float a2 = 49.0f * gw * gh;

    const float px[2] = {p[0].x, p[2].y};
    const float py[2] = {p[0].y, p[3].x};
    const float pw[2] = {p[1].x, p[3].y};
    const float ph[2] = {p[1].y, p[4].x};
    const float pc[2] = {p[2].x, p[4].y};

    float iou[2];
#pragma unroll
    for (int k = 0; k < 2; ++k) {
        const float phw = 3.5f * pw[k], phh = 3.5f * ph[k];
        const float ltx = fmaxf(px[k] - phw, gx - ghw);
        const float rbx = fminf(px[k] + phw, gx + ghw);
        const float lty = fmaxf(py[k] - phh, gy - ghh);
        const float rby = fminf(py[k] + phh, gy + ghh);
        const float w = fmaxf(rbx - ltx, 0.0f);
        const float h = fmaxf(rby - lty, 0.0f);
        const float inter = w * h;
        const float a1 = 49.0f * pw[k] * ph[k];
        iou[k] = inter / (a1 + a2 - inter);
    }

    // argmax first-max tie-break: box1 wins only if strictly greater
    const int r = (iou[1] > iou[0]) ? 1 : 0;
    const float max_iou = fmaxf(iou[0], iou[1]);

    const float dx = px[r] - gx;
    const float dy = py[r] - gy;
    const float dw = sqrtf(pw[r]) - sqrtf(gw);
    const float dh = sqrtf(ph[r]) - sqrtf(gh);
    const float coord = dx * dx + dy * dy + dw * dw + dh * dh;

    const float d = pc[r] - max_iou;
    const float resp_l = d * d;
    const float irr_l = pc[1 - r] * pc[1 - r];

    const float d0 = pc[0] - gc, d1 = pc[1] - gc;
    const float noobj_l = d0 * d0 + d1 * d1;

    float cls = 0.0f;
#pragma unroll
    for (int j = 0; j < 10; ++j) {
        const float ex = p[5 + j].x - gcl[j].x;
        const float ey = p[5 + j].y - gcl[j].y;
        cls += ex * ex + ey * ey;
    }

    // total = 5*coord + 2*resp + 0.5*noobj + cls + irr (resp counted twice)
    float cell_loss = obj * (5.0f * coord + 2.0f * resp_l + irr_l + cls)
                    + noobj * 0.5f * noobj_l;

    // ---- reduce: wave64 shuffle -> block -> plain store (no atomic)
    float v = cell_loss;
#pragma unroll
    for (int off = 32; off > 0; off >>= 1)
        v += __shfl_down(v, off, 64);
    if ((tid & 63) == 0) wsum[tid >> 6] = v;
    __syncthreads();
    if (tid == 0) {
        float s = 0.0f;
#pragma unroll
        for (int w = 0; w < TPB / 64; ++w) s += wsum[w];
        partial[blockIdx.x] = s;
    }
}

__global__ __launch_bounds__(256)
void yolo_reduce(const float* __restrict__ partial,
                 float* __restrict__ out,
                 int n)
{
    __shared__ float wsum[4];
    const int tid = threadIdx.x;

    float s = 0.0f;
    for (int i = tid; i < n; i += 256)
        s += partial[i];

#pragma unroll
    for (int off = 32; off > 0; off >>= 1)
        s += __shfl_down(s, off, 64);
    if ((tid & 63) == 0) wsum[tid >> 6] = s;
    __syncthreads();
    if (tid == 0) {
        float t = wsum[0] + wsum[1] + wsum[2] + wsum[3];
        out[0] = t * INV_B;
    }
}

extern "C" void kernel_launch(void* const* d_in, const int* in_sizes, int n_in,
                              void* d_out, int out_size, void* d_ws, size_t ws_size,
                              hipStream_t stream)
{
    const float* pred = (const float*)d_in[0];
    const float* gt   = (const float*)d_in[1];
    float* out = (float*)d_out;
    float* partial = (float*)d_ws;

    const int ncells = in_sizes[0] / NCH;             // 8192*49 = 401408
    const int nblocks = ncells / CELLS;               // 3136 exact

    yolo_main<<<nblocks, TPB, 0, stream>>>(pred, gt, partial, ncells);
    yolo_reduce<<<1, 256, 0, stream>>>(partial, out, nblocks);
}

// Round 6
// 113.159 us; speedup vs baseline: 1.3849x; 1.3849x over previous
//
#include <hip/hip_runtime.h>

// YOLO-v1 style loss, fused single pass + separate final reduce.
// pred: (8192,7,7,30) f32, gt: (8192,7,7,30) f32 -> scalar f32 (= total/8192).
//
// R5 post-mortem: WRITE_SIZE=94MB exposed register-spill scratch traffic from
// holding 16 float4 in registers across guarded staging. R6: same LDS-
// transpose structure but spill-proof staging: pipelined load->ds_write with
// #pragma unroll 4 (<=8 float4 live), guard-free 7.5-round trip count
// (7*128 + tid<64), __launch_bounds__(128,2) so the allocator targets 2
// waves/EU (no spill) instead of 8 (spill). 30KB LDS -> 5 blocks/CU.

#define NCH 30
#define TPB 128
#define CELLS 128
#define NV4 ((CELLS * NCH) / 4)   // 960 float4 per tensor per block
#define INV_B (1.0f / 8192.0f)

__global__ __launch_bounds__(TPB, 2)
void yolo_main(const float* __restrict__ pred,
               const float* __restrict__ gt,
               float* __restrict__ partial)
{
    __shared__ float sp[CELLS * NCH];   // 15360 B linear pred tile
    __shared__ float sg[CELLS * NCH];   // 15360 B linear gt tile
    __shared__ float wsum[TPB / 64];

    const int tid = threadIdx.x;
    const long long baseF = (long long)blockIdx.x * CELLS * NCH;

    const float4* gp4 = (const float4*)(pred + baseF);
    const float4* gg4 = (const float4*)(gt + baseF);
    float4* lp4 = (float4*)sp;
    float4* lg4 = (float4*)sg;

    // ---- stage: 960 float4 per tensor. 7 full rounds + half round (tid<64).
    // Pipelined copy, bounded live registers (no spill).
#pragma unroll 4
    for (int i = 0; i < 7; ++i) {
        const int idx = tid + i * TPB;
        const float4 a = gp4[idx];
        const float4 b = gg4[idx];
        lp4[idx] = a;
        lg4[idx] = b;
    }
    if (tid < 64) {
        const int idx = tid + 7 * TPB;
        const float4 a = gp4[idx];
        const float4 b = gg4[idx];
        lp4[idx] = a;
        lg4[idx] = b;
    }
    __syncthreads();

    // ---- per-cell loss (verified math, absmax == 0 across R1-R5)
    const float2* cp = (const float2*)(sp + tid * NCH);
    const float2* cg = (const float2*)(sg + tid * NCH);

    float2 p[15];
#pragma unroll
    for (int j = 0; j < 15; ++j) p[j] = cp[j];

    const float2 g0 = cg[0];
    const float2 g1 = cg[1];
    const float2 g2 = cg[2];          // .x = obj flag
    float2 gcl[10];
#pragma unroll
    for (int j = 0; j < 10; ++j) gcl[j] = cg[5 + j];

    const float gx = g0.x, gy = g0.y, gw = g1.x, gh = g1.y;
    const float gc = g2.x;
    const float obj   = (gc > 0.0f) ? 1.0f : 0.0f;
    const float noobj = (gc == 0.0f) ? 1.0f : 0.0f;

    const float ghw = 3.5f * gw, ghh = 3.5f * gh;   // 0.5*GRID*wh
    const float a2 = 49.0f * gw * gh;

    const float px[2] = {p[0].x, p[2].y};
    const float py[2] = {p[0].y, p[3].x};
    const float pw[2] = {p[1].x, p[3].y};
    const float ph[2] = {p[1].y, p[4].x};
    const float pc[2] = {p[2].x, p[4].y};

    float iou[2];
#pragma unroll
    for (int k = 0; k < 2; ++k) {
        const float phw = 3.5f * pw[k], phh = 3.5f * ph[k];
        const float ltx = fmaxf(px[k] - phw, gx - ghw);
        const float rbx = fminf(px[k] + phw, gx + ghw);
        const float lty = fmaxf(py[k] - phh, gy - ghh);
        const float rby = fminf(py[k] + phh, gy + ghh);
        const float w = fmaxf(rbx - ltx, 0.0f);
        const float h = fmaxf(rby - lty, 0.0f);
        const float inter = w * h;
        const float a1 = 49.0f * pw[k] * ph[k];
        iou[k] = inter / (a1 + a2 - inter);
    }

    // argmax first-max tie-break: box1 wins only if strictly greater
    const int r = (iou[1] > iou[0]) ? 1 : 0;
    const float max_iou = fmaxf(iou[0], iou[1]);

    const float dx = px[r] - gx;
    const float dy = py[r] - gy;
    const float dw = sqrtf(pw[r]) - sqrtf(gw);
    const float dh = sqrtf(ph[r]) - sqrtf(gh);
    const float coord = dx * dx + dy * dy + dw * dw + dh * dh;

    const float d = pc[r] - max_iou;
    const float resp_l = d * d;
    const float irr_l = pc[1 - r] * pc[1 - r];

    const float d0 = pc[0] - gc, d1 = pc[1] - gc;
    const float noobj_l = d0 * d0 + d1 * d1;

    float cls = 0.0f;
#pragma unroll
    for (int j = 0; j < 10; ++j) {
        const float ex = p[5 + j].x - gcl[j].x;
        const float ey = p[5 + j].y - gcl[j].y;
        cls += ex * ex + ey * ey;
    }

    // total = 5*coord + 2*resp + 0.5*noobj + cls + irr (resp counted twice)
    const float cell_loss = obj * (5.0f * coord + 2.0f * resp_l + irr_l + cls)
                          + noobj * 0.5f * noobj_l;

    // ---- reduce: wave64 shuffle -> block -> plain store (no atomic)
    float v = cell_loss;
#pragma unroll
    for (int off = 32; off > 0; off >>= 1)
        v += __shfl_down(v, off, 64);
    if ((tid & 63) == 0) wsum[tid >> 6] = v;
    __syncthreads();
    if (tid == 0) {
        float s = 0.0f;
#pragma unroll
        for (int w = 0; w < TPB / 64; ++w) s += wsum[w];
        partial[blockIdx.x] = s;
    }
}

__global__ __launch_bounds__(256)
void yolo_reduce(const float* __restrict__ partial,
                 float* __restrict__ out,
                 int n)
{
    __shared__ float wsum[4];
    const int tid = threadIdx.x;

    float s = 0.0f;
    for (int i = tid; i < n; i += 256)
        s += partial[i];

#pragma unroll
    for (int off = 32; off > 0; off >>= 1)
        s += __shfl_down(s, off, 64);
    if ((tid & 63) == 0) wsum[tid >> 6] = s;
    __syncthreads();
    if (tid == 0) {
        float t = wsum[0] + wsum[1] + wsum[2] + wsum[3];
        out[0] = t * INV_B;
    }
}

extern "C" void kernel_launch(void* const* d_in, const int* in_sizes, int n_in,
                              void* d_out, int out_size, void* d_ws, size_t ws_size,
                              hipStream_t stream)
{
    const float* pred = (const float*)d_in[0];
    const float* gt   = (const float*)d_in[1];
    float* out = (float*)d_out;
    float* partial = (float*)d_ws;

    const int ncells = in_sizes[0] / NCH;   // 8192*49 = 401408
    const int nblocks = ncells / CELLS;     // 3136 exact

    yolo_main<<<nblocks, TPB, 0, stream>>>(pred, gt, partial);
    yolo_reduce<<<1, 256, 0, stream>>>(partial, out, nblocks);
}